// Round 16
// baseline (98.525 us; speedup 1.0000x reference)
//
#include <hip/hip_runtime.h>
#include <hip/hip_bf16.h>

typedef __attribute__((ext_vector_type(8))) short short8;
typedef __attribute__((ext_vector_type(16))) float f32x16;
typedef __fp16 h2 __attribute__((ext_vector_type(2)));
typedef unsigned short ushort_t;

#define DEVFN static __device__ __forceinline__
#define MFMA32 __builtin_amdgcn_mfma_f32_32x32x16_bf16

DEVFN float bf2f(unsigned short u){
  union { unsigned int i; float f; } v; v.i = ((unsigned int)u) << 16; return v.f;
}
DEVFN unsigned short f2bf(float f){
  unsigned int u = __float_as_uint(f);
  unsigned int r = u + 0x7FFFu + ((u >> 16) & 1u);
  return (unsigned short)(r >> 16);
}
DEVFN unsigned int pkbf(float a, float b){
  unsigned int r;
  asm("v_cvt_pk_bf16_f32 %0, %1, %2" : "=v"(r) : "v"(a), "v"(b));
  return r;
}
DEVFN h2 pkrtz(float a, float b){ return __builtin_amdgcn_cvt_pkrtz(a, b); }
DEVFN h2 u2h(unsigned int u){ union { unsigned int u; h2 h; } v; v.u = u; return v.h; }
DEVFN float h2f(ushort_t u){ union { ushort_t u; __fp16 h; } v; v.u = u; return (float)v.h; }
// HW 2-way f16 dot with f32 accumulate (verified round 15)
DEVFN float dot2(h2 a, h2 b, float c){
  float r;
  asm("v_dot2_f32_f16 %0, %1, %2, %3" : "=v"(r) : "v"(a), "v"(b), "v"(c));
  return r;
}
DEVFN float tanh_fast(float x){
  float t = __builtin_amdgcn_exp2f(x * 2.885390081777926815f);
  return 1.0f - 2.0f * __builtin_amdgcn_rcpf(t + 1.0f);
}
// shared A/B K-slot mapping for 32x32x16 MFMA fragments
DEVFN int kmap(int h, int j){ return 4*h + (j & 3) + 8*(j >> 2); }

// ---------------- weight bake (coalesced reads, scattered stores) ----------------
// wfrag (hw): ((f*4 + gq)*2 + nh)*3072 + (l*2 + nt)*512 + lane*8 + j
__global__ void bake_w0(const float* __restrict__ wx0, const float* __restrict__ wy0,
                        ushort_t* __restrict__ wfrag){
  int idx = blockIdx.x * 256 + threadIdx.x;   // < 524288
  int g = idx & 63; int r = idx >> 6;
  int f = r & 63; r >>= 6;
  int k = r & 63; int path = r >> 6;
  const float* w = path ? wy0 : wx0;
  const float* src = w + ((size_t)(k*64 + f)*64 + g)*3;
  float v0 = src[0], v1 = src[1], v2 = src[2];
  int gq = g >> 4, gl = g & 15;
  int h = (gl >> 2) & 1;
  int j = (gl & 3) | ((gl >> 3) << 2);
  int lane = h*32 + (k & 31);
  int nt = k >> 5;
  size_t base = (size_t)((f*4 + gq)*2 + path)*3072 + (size_t)lane*8 + j;
  wfrag[base + 0*512 + (size_t)nt*512] = f2bf(v0);
  wfrag[base + 2*512 + (size_t)nt*512] = f2bf(v1);
  wfrag[base + 4*512 + (size_t)nt*512] = f2bf(v2);
}

__global__ void bake_wh(const float* __restrict__ wxh, const float* __restrict__ wyh,
                        ushort_t* __restrict__ whfrag){
  int slot = blockIdx.x * 256 + threadIdx.x;      // < 2048
  int lane = slot & 63;
  int q = slot >> 6;
  int nt = q & 1; q >>= 1;
  int c  = q & 3; q >>= 2;
  int path = q & 1; int layer = q >> 1;
  const float* w = path ? wyh : wxh;
  int n = nt*32 + (lane & 31);
  int h = lane >> 5;
  unsigned int pk[4];
#pragma unroll
  for (int jj = 0; jj < 4; ++jj){
    int k0 = c*16 + kmap(h, 2*jj);
    int k1 = c*16 + kmap(h, 2*jj + 1);
    unsigned int b0 = f2bf(w[layer*4096 + k0*64 + n]);
    unsigned int b1 = f2bf(w[layer*4096 + k1*64 + n]);
    pk[jj] = b0 | (b1 << 16);
  }
  *reinterpret_cast<uint4*>(whfrag + (size_t)slot * 8) = make_uint4(pk[0], pk[1], pk[2], pk[3]);
}

__global__ void bake_wf(const float* __restrict__ wxf, const float* __restrict__ wyf,
                        ushort_t* __restrict__ wffrag){
  int slot = blockIdx.x * 256 + threadIdx.x;      // < 3072
  int lane = slot & 63;
  int q = slot >> 6;            // < 48
  int ntf = q % 6;
  int q2 = q / 6;
  int c = q2 & 3; int path = q2 >> 2;
  const float* w = path ? wyf : wxf;
  int n = ntf*32 + (lane & 31);
  int lw = n >> 6, fw = n & 63;
  int h = lane >> 5;
  unsigned int pk[4];
#pragma unroll
  for (int jj = 0; jj < 4; ++jj){
    int k0 = c*16 + kmap(h, 2*jj);
    int k1 = c*16 + kmap(h, 2*jj + 1);
    unsigned int b0 = f2bf(w[(lw*64 + fw)*64 + k0]);
    unsigned int b1 = f2bf(w[(lw*64 + fw)*64 + k1]);
    pk[jj] = b0 | (b1 << 16);
  }
  *reinterpret_cast<uint4*>(wffrag + (size_t)slot * 8) = make_uint4(pk[0], pk[1], pk[2], pk[3]);
}

// ---------------- main fused GEMM (fh-split, conflict-free strides, 4 WG/CU) ----------------
// Grid 1024 = Mblk(256, 32 pts) x nh(2) x fh(2); WG 256 thr = 4 waves = gq.
// LDS phases (alloc 36992 B -> 4 WG/CU):
//   A: gate-y f16 [32p][195 d] (s0..3 per g at g*3 d)    24960 B  stride 195%32=3 ok
//   B: x f16     [32p][578 h] (9h per g at g*9 h)        36992 B  stride 289%32=1 ok
//   C: y-half f16 [32p][165 d] (10h per f at f*5 d)      21120 B  stride 165%32=5 ok
//      red [64][33] f32 @21120..29568
struct BSet { uint4 b[6]; };
union U4 { uint4 u; short8 s; };

__global__ __launch_bounds__(256)
void gemm16(const float* __restrict__ x, const float* __restrict__ y,
            const ushort_t* __restrict__ wfrag, float* __restrict__ mixp){
  extern __shared__ char lds[];
  unsigned int* Ld = (unsigned int*)lds;
  ushort_t* Lh = (ushort_t*)lds;
  float (*red)[33] = (float (*)[33])(lds + 21120);

  const int bid = blockIdx.x;
  const int id = (bid & 7)*128 + (bid >> 3);              // XCD bijection (1024=8*128)
  const int fh = id & 1, nh = (id >> 1) & 1, mb = id >> 2;
  const int pbase = mb * 32;

  const int t = threadIdx.x, lane = t & 63, gq = t >> 6;
  const int h = lane >> 5, pr = lane & 31;

  const float* xb = x + (size_t)pbase * 576;
  const float* yb = y + (size_t)pbase * 576;

  // ---- phase A: stage gate-y (s<4) f16, coalesced full-y float4 reads ----
#pragma unroll
  for (int c = 0; c < 18; ++c){
    int q = t + c*256;                 // < 4608
    int p = q / 144, off = (q - p*144) * 4;
    float4 v = *(const float4*)(yb + p*576 + off);
#pragma unroll
    for (int i = 0; i < 4; ++i){
      int flat = off + i;
      int g = flat / 9, s = flat - g*9;
      if (s < 4){
        float vv = (i==0) ? v.x : (i==1) ? v.y : (i==2) ? v.z : v.w;
        union { __fp16 hf; ushort_t u; } cv; cv.hf = (__fp16)vv;
        Lh[(p*195 + g*3)*2 + s] = cv.u;
      }
    }
  }
  __syncthreads();

  // gate-y -> regs for this lane's 8 g
  float gy[8][4];
#pragma unroll
  for (int j = 0; j < 8; ++j){
    const int g = gq*16 + kmap(h, j);
    unsigned int d0 = Ld[pr*195 + g*3];
    unsigned int d1 = Ld[pr*195 + g*3 + 1];
    h2 y01 = u2h(d0), y23 = u2h(d1);
    gy[j][0] = (float)y01[0]; gy[j][1] = (float)y01[1];
    gy[j][2] = (float)y23[0]; gy[j][3] = (float)y23[1];
  }
  __syncthreads();

  // ---- phase B: stage full x f16 [p][578h], coalesced float4 reads ----
#pragma unroll
  for (int c = 0; c < 18; ++c){
    int q = t + c*256;
    int p = q / 144, off = (q - p*144) * 4;
    float4 v = *(const float4*)(xb + p*576 + off);
#pragma unroll
    for (int i = 0; i < 4; ++i){
      int flat = off + i;
      int g = flat / 9, s = flat - g*9;
      float vv = (i==0) ? v.x : (i==1) ? v.y : (i==2) ? v.z : v.w;
      union { __fp16 hf; ushort_t u; } cv; cv.hf = (__fp16)vv;
      Lh[p*578 + g*9 + s] = cv.u;
    }
  }
  __syncthreads();

  // ---- xg from LDS x (u16 reads) + reg gate-y ----
  h2 xg[8][5];
#pragma unroll
  for (int j = 0; j < 8; ++j){
    const int g = gq*16 + kmap(h, j);
    const ushort_t* xp = Lh + pr*578 + g*9;
    float x0 = h2f(xp[0]), x1 = h2f(xp[1]), x2 = h2f(xp[2]), x3 = h2f(xp[3]);
    float x4 = h2f(xp[4]), x5 = h2f(xp[5]), x6 = h2f(xp[6]), x7 = h2f(xp[7]);
    float x8 = h2f(xp[8]);
    float y0 = gy[j][0], y1 = gy[j][1], y2 = gy[j][2], y3 = gy[j][3];
    float gate = (x2*y3 - x3*y2)*y0 + (x3*y1 - x1*y3)*y1 + (x1*y2 - x2*y1)*y2;
    xg[j][0] = pkrtz(x0*gate, x1*gate);
    xg[j][1] = pkrtz(x2*gate, x3*gate);
    xg[j][2] = pkrtz(x4*gate, x5*gate);
    xg[j][3] = pkrtz(x6*gate, x7*gate);
    xg[j][4] = pkrtz(x8*gate, 0.f);
  }
  __syncthreads();

  // ---- phase C: stage this fh-half of y f16 [p][330h] ----
#pragma unroll
  for (int c = 0; c < 9; ++c){
    int q = t + c*256;                 // < 2304
    int p = q / 72, off = (q - p*72) * 4;
    float4 v = *(const float4*)(yb + p*576 + fh*288 + off);
#pragma unroll
    for (int i = 0; i < 4; ++i){
      int flat = off + i;
      int f = flat / 9, s = flat - f*9;
      float vv = (i==0) ? v.x : (i==1) ? v.y : (i==2) ? v.z : v.w;
      union { __fp16 hf; ushort_t u; } cv; cv.hf = (__fp16)vv;
      Lh[p*330 + f*10 + s] = cv.u;
    }
  }
  __syncthreads();

  // ---- main loop: 32 steps, barrier-free (round-14 loop + dot2) ----
  f32x16 acc0, acc1;
#pragma unroll
  for (int e = 0; e < 16; ++e){ acc0[e] = 0.f; acc1[e] = 0.f; }

  const ushort_t* wt = wfrag + (size_t)(fh*32)*24576
                             + (size_t)(gq*2 + nh)*3072 + (size_t)lane*8;
  const unsigned int* yrow = Ld + pr*165;

  auto ldB = [&](int f, BSet& B){
    const ushort_t* p0 = wt + (size_t)f * 24576;
#pragma unroll
    for (int i = 0; i < 6; ++i) B.b[i] = *reinterpret_cast<const uint4*>(p0 + i*512);
  };
  auto ldYh = [&](int f, unsigned int* Yr){
#pragma unroll
    for (int d = 0; d < 5; ++d) Yr[d] = yrow[f*5 + d];
  };
  auto agen_mfma = [&](const unsigned int* Yr, const BSet& B){
    h2 y0m = u2h(Yr[0] & 0xFFFFu);
    h2 y1m = u2h(Yr[0] & 0xFFFF0000u);
    h2 y23 = u2h(Yr[1]), y45 = u2h(Yr[2]), y67 = u2h(Yr[3]);
    h2 y8p = u2h(Yr[4] & 0xFFFFu);
    float a0[8], a1[8], a2[8];
#pragma unroll
    for (int j = 0; j < 8; ++j){
      a0[j] = dot2(xg[j][0], y0m, 0.f);
      a1[j] = dot2(xg[j][1], y23, dot2(xg[j][0], y1m, 0.f));
      a2[j] = dot2(xg[j][4], y8p, dot2(xg[j][3], y67, dot2(xg[j][2], y45, 0.f)));
    }
    U4 fA0, fA1, fA2;
    fA0.u = make_uint4(pkbf(a0[0],a0[1]), pkbf(a0[2],a0[3]), pkbf(a0[4],a0[5]), pkbf(a0[6],a0[7]));
    fA1.u = make_uint4(pkbf(a1[0],a1[1]), pkbf(a1[2],a1[3]), pkbf(a1[4],a1[5]), pkbf(a1[6],a1[7]));
    fA2.u = make_uint4(pkbf(a2[0],a2[1]), pkbf(a2[2],a2[3]), pkbf(a2[4],a2[5]), pkbf(a2[6],a2[7]));
    U4 b0, b1, b2, b3, b4, b5;
    b0.u = B.b[0]; b1.u = B.b[1]; b2.u = B.b[2];
    b3.u = B.b[3]; b4.u = B.b[4]; b5.u = B.b[5];
    acc0 = MFMA32(fA0.s, b0.s, acc0, 0, 0, 0);
    acc1 = MFMA32(fA0.s, b1.s, acc1, 0, 0, 0);
    acc0 = MFMA32(fA1.s, b2.s, acc0, 0, 0, 0);
    acc1 = MFMA32(fA1.s, b3.s, acc1, 0, 0, 0);
    acc0 = MFMA32(fA2.s, b4.s, acc0, 0, 0, 0);
    acc1 = MFMA32(fA2.s, b5.s, acc1, 0, 0, 0);
  };

  BSet Ba, Bb;
  unsigned int Ya[5], Yb[5];
  ldB(0, Ba); ldYh(0, Ya);
  ldB(1, Bb); ldYh(1, Yb);

#pragma unroll 1
  for (int s = 0; s < 32; s += 2){
    agen_mfma(Ya, Ba);
    const int s2 = (s + 2 < 32) ? s + 2 : 31;
    ldB(s2, Ba); ldYh(s2, Ya);
    agen_mfma(Yb, Bb);
    const int s3 = (s + 3 < 32) ? s + 3 : 31;
    ldB(s3, Bb); ldYh(s3, Yb);
  }

  // ---- in-WG reduction over gq (serialized through one 8.4KB buffer) ----
  __syncthreads();
#pragma unroll 1
  for (int rr = 1; rr <= 3; ++rr){
    if (gq == rr){
#pragma unroll
      for (int e = 0; e < 16; ++e){
        red[lane][e]      = acc0[e];
        red[lane][16 + e] = acc1[e];
      }
    }
    __syncthreads();
    if (gq == 0){
#pragma unroll
      for (int e = 0; e < 16; ++e){
        acc0[e] += red[lane][e];
        acc1[e] += red[lane][16 + e];
      }
    }
    __syncthreads();
  }
  if (gq == 0){
    float* mp = mixp + (size_t)fh * 1048576;
#pragma unroll
    for (int e = 0; e < 16; ++e){
      int rowm = (e & 3) + 8*(e >> 2) + 4*h;
      float* d = mp + (size_t)(pbase + rowm)*128 + nh*64 + pr;
      d[0]  = acc0[e];
      d[32] = acc1[e];
    }
  }
}

// ---------------- MLP core: mix(sum of 2 fh-partials) -> MLP -> final -> ox/oy ----------------
__global__ __launch_bounds__(256, 1)
void mlp_core(const ushort_t* __restrict__ whfrag,
              const ushort_t* __restrict__ wffrag,
              const float* __restrict__ mixp,
              ushort_t* __restrict__ oxg, ushort_t* __restrict__ oyg){
  extern __shared__ char ldsm[];
  ushort_t* hw = (ushort_t*)ldsm;
  const int t = threadIdx.x;
  const long pbase = (long)blockIdx.x * 32;

  {  // load mix = sum of 2 fh-partials -> act buf0 (bf16)
    int p = t >> 3, n0 = (t & 7) * 16;
    const float* src = mixp + (pbase + p)*128 + n0;
    int path = n0 >> 6, nn = n0 & 63;
    ushort_t* dst = hw + (path*2)*2176 + p*68 + nn;
#pragma unroll
    for (int q2 = 0; q2 < 16; ++q2){
      float v = src[q2] + src[q2 + 1048576];
      dst[q2] = f2bf(v);
    }
  }
  __syncthreads();

  const int w = t >> 6, lane = t & 63;
  const int path = w >> 1, ntw = w & 1;
  const int prow = lane & 31, h = lane >> 5;
  int cur = 0;

#pragma unroll
  for (int layer = 0; layer < 2; ++layer){
    const ushort_t* act = hw + (path*2 + cur)*2176;
    f32x16 acc;
#pragma unroll
    for (int r = 0; r < 16; ++r) acc[r] = 0.f;
#pragma unroll
    for (int c = 0; c < 4; ++c){
      int ab = prow*68 + c*16 + 4*h;
      ushort4 lo = *(const ushort4*)&act[ab];
      ushort4 hi = *(const ushort4*)&act[ab + 8];
      short8 av; av[0]=lo.x; av[1]=lo.y; av[2]=lo.z; av[3]=lo.w;
      av[4]=hi.x; av[5]=hi.y; av[6]=hi.z; av[7]=hi.w;
      short8 bv = *(const short8*)(whfrag + ((((layer*2 + path)*4 + c)*2 + ntw)*512 + lane*8));
      acc = MFMA32(av, bv, acc, 0, 0, 0);
    }
    ushort_t* nact = hw + (path*2 + (cur ^ 1))*2176;
#pragma unroll
    for (int r = 0; r < 16; ++r){
      int p = (r & 3) + 8*(r >> 2) + 4*h;
      nact[p*68 + ntw*32 + prow] = f2bf(tanh_fast(acc[r]));
    }
    cur ^= 1;
    __syncthreads();
  }

  {  // final einsum: o[p][n=l*64+f] -> global ox/oy (bf16)
    const ushort_t* act = hw + (path*2 + cur)*2176;
    ushort_t* og = (path ? oyg : oxg) + (size_t)pbase * 196;
#pragma unroll
    for (int e = 0; e < 3; ++e){
      int ntf = ntw*3 + e;
      f32x16 acc;
#pragma unroll
      for (int r = 0; r < 16; ++r) acc[r] = 0.f;
#pragma unroll
      for (int c = 0; c < 4; ++c){
        int ab = prow*68 + c*16 + 4*h;
        ushort4 lo = *(const ushort4*)&act[ab];
        ushort4 hi = *(const ushort4*)&act[ab + 8];
        short8 av; av[0]=lo.x; av[1]=lo.y; av[2]=lo.z; av[3]=lo.w;
        av[4]=hi.x; av[5]=hi.y; av[6]=hi.z; av[7]=hi.w;
        short8 bv = *(const short8*)(wffrag + (((path*4 + c)*6 + ntf)*512 + lane*8));
        acc = MFMA32(av, bv, acc, 0, 0, 0);
      }
#pragma unroll
      for (int r = 0; r < 16; ++r){
        int p = (r & 3) + 8*(r >> 2) + 4*h;
        og[(size_t)p*196 + ntf*32 + prow] = f2bf(tanh_fast(acc[r]));
      }
    }
  }
}

// ---------------- epilogue: out = ox[deg]*x*gate + oy[deg]*y (coalesced) ----------------
__global__ __launch_bounds__(256)
void epilogue_k(const float* __restrict__ x, const float* __restrict__ y,
                const ushort_t* __restrict__ oxg, const ushort_t* __restrict__ oyg,
                float* __restrict__ out){
  __shared__ float xs[2304], ys[2304], os[2304];
  const int t = threadIdx.x;
  const long pbase = (long)blockIdx.x * 4;
  const float4* xb = (const float4*)(x + pbase*576);
  const float4* yb = (const float4*)(y + pbase*576);
#pragma unroll
  for (int c = 0; c < 3; ++c){
    int q = t + c*256;
    if (q < 576){
      ((float4*)xs)[q] = xb[q];
      ((float4*)ys)[q] = yb[q];
    }
  }
  __syncthreads();

  const int pp = t >> 6, fq = t & 63;
  {
    const float* xr = &xs[pp*576 + fq*9];
    const float* yr = &ys[pp*576 + fq*9];
    float xv[9], yv[9];
#pragma unroll
    for (int s = 0; s < 9; ++s){ xv[s] = xr[s]; yv[s] = yr[s]; }
    float c0 = xv[2]*yv[3] - xv[3]*yv[2];
    float c1 = xv[3]*yv[1] - xv[1]*yv[3];
    float c2 = xv[1]*yv[2] - xv[2]*yv[1];
    float gate = c0*yv[0] + c1*yv[1] + c2*yv[2];
    const size_t prow = (size_t)(pbase + pp) * 196;
    float ox0 = bf2f(oxg[prow + fq]);
    float ox1 = bf2f(oxg[prow + 64 + fq]);
    float ox2 = bf2f(oxg[prow + 128 + fq]);
    float oy0 = bf2f(oyg[prow + fq]);
    float oy1 = bf2f(oyg[prow + 64 + fq]);
    float oy2 = bf2f(oyg[prow + 128 + fq]);
    float* orow = &os[pp*576 + fq*9];
    orow[0] = ox0*xv[0]*gate + oy0*yv[0];
#pragma unroll
    for (int s = 1; s < 4; ++s) orow[s] = ox1*xv[s]*gate + oy1*yv[s];
#pragma unroll
    for (int s = 4; s < 9; ++s) orow[s] = ox2*xv[s]*gate + oy2*yv[s];
  }
  __syncthreads();

  float4* ob = (float4*)(out + pbase*576);
#pragma unroll
  for (int c = 0; c < 3; ++c){
    int q = t + c*256;
    if (q < 576) ob[q] = ((const float4*)os)[q];
  }
}

extern "C" void kernel_launch(void* const* d_in, const int* in_sizes, int n_in,
                              void* d_out, int out_size, void* d_ws, size_t ws_size,
                              hipStream_t stream){
  (void)in_sizes; (void)n_in; (void)out_size; (void)ws_size;
  const float* x   = (const float*)d_in[0];
  const float* y   = (const float*)d_in[1];
  const float* wx0 = (const float*)d_in[2];
  const float* wy0 = (const float*)d_in[3];
  const float* wxh = (const float*)d_in[4];
  const float* wyh = (const float*)d_in[5];
  const float* wxf = (const float*)d_in[6];
  const float* wyf = (const float*)d_in[7];
  float* out = (float*)d_out;
  char* ws = (char*)d_ws;
  ushort_t* wfrag  = (ushort_t*)(ws);              //  3,145,728 B
  ushort_t* whfrag = (ushort_t*)(ws + 3145728);    //     32,768 B
  ushort_t* wffrag = (ushort_t*)(ws + 3178496);    //     49,152 B
  float* mixp      = (float*)(ws + 3227648);       //  2 x 4,194,304 B
  ushort_t* oxg    = (ushort_t*)(ws + 11616256);   //  3,211,264 B
  ushort_t* oyg    = (ushort_t*)(ws + 14827520);   //  3,211,264 B

  (void)hipFuncSetAttribute((const void*)gemm16,
        hipFuncAttributeMaxDynamicSharedMemorySize, 36992);

  hipLaunchKernelGGL(bake_w0, dim3(2048), dim3(256), 0, stream, wx0, wy0, wfrag);
  hipLaunchKernelGGL(bake_wh, dim3(8),    dim3(256), 0, stream, wxh, wyh, whfrag);
  hipLaunchKernelGGL(bake_wf, dim3(12),   dim3(256), 0, stream, wxf, wyf, wffrag);
  hipLaunchKernelGGL(gemm16,  dim3(1024), dim3(256), 36992, stream, x, y, wfrag, mixp);
  hipLaunchKernelGGL(mlp_core, dim3(256), dim3(256), 17408, stream, whfrag, wffrag, mixp, oxg, oyg);
  hipLaunchKernelGGL(epilogue_k, dim3(2048), dim3(256), 0, stream, x, y, oxg, oyg, out);
}

// Round 17
// 82.820 us; speedup vs baseline: 1.1896x; 1.1896x over previous
//
#include <hip/hip_runtime.h>
#include <hip/hip_bf16.h>

typedef __attribute__((ext_vector_type(8))) short short8;
typedef __attribute__((ext_vector_type(16))) float f32x16;
typedef __fp16 h2 __attribute__((ext_vector_type(2)));
typedef unsigned short ushort_t;

#define DEVFN static __device__ __forceinline__
#define MFMA32 __builtin_amdgcn_mfma_f32_32x32x16_bf16

DEVFN float bf2f(unsigned short u){
  union { unsigned int i; float f; } v; v.i = ((unsigned int)u) << 16; return v.f;
}
DEVFN unsigned short f2bf(float f){
  unsigned int u = __float_as_uint(f);
  unsigned int r = u + 0x7FFFu + ((u >> 16) & 1u);
  return (unsigned short)(r >> 16);
}
DEVFN unsigned int pkbf(float a, float b){
  unsigned int r;
  asm("v_cvt_pk_bf16_f32 %0, %1, %2" : "=v"(r) : "v"(a), "v"(b));
  return r;
}
DEVFN h2 pkrtz(float a, float b){ return __builtin_amdgcn_cvt_pkrtz(a, b); }
DEVFN h2 u2h(unsigned int u){ union { unsigned int u; h2 h; } v; v.u = u; return v.h; }
// HW 2-way f16 dot with f32 accumulate (verified round 15)
DEVFN float dot2(h2 a, h2 b, float c){
  float r;
  asm("v_dot2_f32_f16 %0, %1, %2, %3" : "=v"(r) : "v"(a), "v"(b), "v"(c));
  return r;
}
DEVFN float tanh_fast(float x){
  float t = __builtin_amdgcn_exp2f(x * 2.885390081777926815f);
  return 1.0f - 2.0f * __builtin_amdgcn_rcpf(t + 1.0f);
}
// shared A/B K-slot mapping for 32x32x16 MFMA fragments
DEVFN int kmap(int h, int j){ return 4*h + (j & 3) + 8*(j >> 2); }

// ---------------- weight bake (coalesced reads, scattered stores) ----------------
// wfrag (hw): ((f*4 + gq)*2 + nh)*3072 + (l*2 + nt)*512 + lane*8 + j
__global__ void bake_w0(const float* __restrict__ wx0, const float* __restrict__ wy0,
                        ushort_t* __restrict__ wfrag){
  int idx = blockIdx.x * 256 + threadIdx.x;   // < 524288
  int g = idx & 63; int r = idx >> 6;
  int f = r & 63; r >>= 6;
  int k = r & 63; int path = r >> 6;
  const float* w = path ? wy0 : wx0;
  const float* src = w + ((size_t)(k*64 + f)*64 + g)*3;
  float v0 = src[0], v1 = src[1], v2 = src[2];      // coalesced (12B stride over g)
  int gq = g >> 4, gl = g & 15;
  int h = (gl >> 2) & 1;
  int j = (gl & 3) | ((gl >> 3) << 2);
  int lane = h*32 + (k & 31);
  int nt = k >> 5;
  size_t base = (size_t)((f*4 + gq)*2 + path)*3072 + (size_t)lane*8 + j;
  wfrag[base + 0*512 + (size_t)nt*512] = f2bf(v0);           // l=0
  wfrag[base + 2*512 + (size_t)nt*512] = f2bf(v1);           // l=1
  wfrag[base + 4*512 + (size_t)nt*512] = f2bf(v2);           // l=2
}

// merged small-weight bake: blocks 0..7 -> whfrag (2048 slots), 8..19 -> wffrag (3072 slots)
__global__ void bake_ws(const float* __restrict__ wxh, const float* __restrict__ wyh,
                        const float* __restrict__ wxf, const float* __restrict__ wyf,
                        ushort_t* __restrict__ whfrag, ushort_t* __restrict__ wffrag){
  int bid = blockIdx.x;
  if (bid < 8){
    int slot = bid * 256 + threadIdx.x;           // < 2048
    int lane = slot & 63;
    int q = slot >> 6;
    int nt = q & 1; q >>= 1;
    int c  = q & 3; q >>= 2;
    int path = q & 1; int layer = q >> 1;
    const float* w = path ? wyh : wxh;
    int n = nt*32 + (lane & 31);
    int h = lane >> 5;
    unsigned int pk[4];
#pragma unroll
    for (int jj = 0; jj < 4; ++jj){
      int k0 = c*16 + kmap(h, 2*jj);
      int k1 = c*16 + kmap(h, 2*jj + 1);
      unsigned int b0 = f2bf(w[layer*4096 + k0*64 + n]);
      unsigned int b1 = f2bf(w[layer*4096 + k1*64 + n]);
      pk[jj] = b0 | (b1 << 16);
    }
    *reinterpret_cast<uint4*>(whfrag + (size_t)slot * 8) = make_uint4(pk[0], pk[1], pk[2], pk[3]);
  } else {
    int slot = (bid - 8) * 256 + threadIdx.x;     // < 3072
    int lane = slot & 63;
    int q = slot >> 6;            // < 48
    int ntf = q % 6;
    int q2 = q / 6;
    int c = q2 & 3; int path = q2 >> 2;
    const float* w = path ? wyf : wxf;
    int n = ntf*32 + (lane & 31);
    int lw = n >> 6, fw = n & 63;
    int h = lane >> 5;
    unsigned int pk[4];
#pragma unroll
    for (int jj = 0; jj < 4; ++jj){
      int k0 = c*16 + kmap(h, 2*jj);
      int k1 = c*16 + kmap(h, 2*jj + 1);
      unsigned int b0 = f2bf(w[(lw*64 + fw)*64 + k0]);
      unsigned int b1 = f2bf(w[(lw*64 + fw)*64 + k1]);
      pk[jj] = b0 | (b1 << 16);
    }
    *reinterpret_cast<uint4*>(wffrag + (size_t)slot * 8) = make_uint4(pk[0], pk[1], pk[2], pk[3]);
  }
}

// ---------------- main fused GEMM (round-15 structure + s_setprio) ----------------
// Grid 512 = Mblk(256, 32 pts) x nh(2); WG 256 thr = 4 waves = gq quarters.
// LDS: YH f16 [32 p][325 dwords] @0 (41600 B) ; red [64][33] f32 @41600 (8448 B)
struct BSet { uint4 b[6]; };
union U4 { uint4 u; short8 s; };

__global__ __launch_bounds__(256)
void gemm10(const float* __restrict__ x, const float* __restrict__ y,
            const ushort_t* __restrict__ wfrag, float* __restrict__ mix){
  extern __shared__ char lds[];
  unsigned int* YHd = (unsigned int*)lds;                 // [32][325] dwords
  ushort_t* YHh = (ushort_t*)lds;
  float (*red)[33] = (float (*)[33])(lds + 41600);        // [64][33]

  const int bid = blockIdx.x;
  const int id = (bid & 7)*64 + (bid >> 3);               // XCD-chunked bijection
  const int nh = id & 1, mb = id >> 1;
  const int pbase = mb * 32;

  const int t = threadIdx.x, lane = t & 63, gq = t >> 6;
  const int h = lane >> 5, pr = lane & 31;

  const float* yb = y + (size_t)pbase * 576;

  // ---- stage y as f16 into LDS (coalesced float4 reads) ----
#pragma unroll
  for (int c = 0; c < 18; ++c){
    int q = t + c*256;                 // < 4608
    int p = q / 144, off = (q - p*144) * 4;
    float4 v = *(const float4*)(yb + p*576 + off);
#pragma unroll
    for (int i = 0; i < 4; ++i){
      int flat = off + i;
      int f = flat / 9, s = flat - f*9;
      float vv = (i==0) ? v.x : (i==1) ? v.y : (i==2) ? v.z : v.w;
      union { __fp16 hf; ushort_t u; } cv; cv.hf = (__fp16)vv;
      YHh[p*650 + f*10 + s] = cv.u;
    }
  }
  __syncthreads();

  // ---- xg init: x via per-lane scalar loads (one-time), y from LDS ----
  h2 xg[8][5];
#pragma unroll
  for (int j = 0; j < 8; ++j){
    const int g = gq*16 + kmap(h, j);
    const float* xp = x + (size_t)(pbase + pr)*576 + g*9;
    unsigned int yd0 = YHd[pr*325 + g*5 + 0];
    unsigned int yd1 = YHd[pr*325 + g*5 + 1];
    h2 y01 = u2h(yd0), y23v = u2h(yd1);
    float y0 = (float)y01[0], y1 = (float)y01[1];
    float y2 = (float)y23v[0], y3 = (float)y23v[1];
    float x1 = xp[1], x2 = xp[2], x3 = xp[3];
    float gate = (x2*y3 - x3*y2)*y0 + (x3*y1 - x1*y3)*y1 + (x1*y2 - x2*y1)*y2;
    xg[j][0] = pkrtz(xp[0]*gate, x1*gate);
    xg[j][1] = pkrtz(x2*gate, x3*gate);
    xg[j][2] = pkrtz(xp[4]*gate, xp[5]*gate);
    xg[j][3] = pkrtz(xp[6]*gate, xp[7]*gate);
    xg[j][4] = pkrtz(xp[8]*gate, 0.f);
  }

  // ---- main loop ----
  f32x16 acc0, acc1;
#pragma unroll
  for (int e = 0; e < 16; ++e){ acc0[e] = 0.f; acc1[e] = 0.f; }

  const ushort_t* wt = wfrag + (size_t)(gq*2 + nh)*3072 + (size_t)lane*8;
  const unsigned int* yrow = YHd + pr*325;

  auto ldB = [&](int f, BSet& B){
    const ushort_t* p0 = wt + (size_t)f * 24576;
#pragma unroll
    for (int i = 0; i < 6; ++i) B.b[i] = *reinterpret_cast<const uint4*>(p0 + i*512);
  };
  auto ldYh = [&](int f, unsigned int* Yr){
#pragma unroll
    for (int d = 0; d < 5; ++d) Yr[d] = yrow[f*5 + d];
  };
  auto agen_mfma = [&](const unsigned int* Yr, const BSet& B){
    h2 y0m = u2h(Yr[0] & 0xFFFFu);
    h2 y1m = u2h(Yr[0] & 0xFFFF0000u);
    h2 y23 = u2h(Yr[1]), y45 = u2h(Yr[2]), y67 = u2h(Yr[3]);
    h2 y8p = u2h(Yr[4] & 0xFFFFu);
    float a0[8], a1[8], a2[8];
#pragma unroll
    for (int j = 0; j < 8; ++j){
      a0[j] = dot2(xg[j][0], y0m, 0.f);
      a1[j] = dot2(xg[j][1], y23, dot2(xg[j][0], y1m, 0.f));
      a2[j] = dot2(xg[j][4], y8p, dot2(xg[j][3], y67, dot2(xg[j][2], y45, 0.f)));
    }
    U4 fA0, fA1, fA2;
    fA0.u = make_uint4(pkbf(a0[0],a0[1]), pkbf(a0[2],a0[3]), pkbf(a0[4],a0[5]), pkbf(a0[6],a0[7]));
    fA1.u = make_uint4(pkbf(a1[0],a1[1]), pkbf(a1[2],a1[3]), pkbf(a1[4],a1[5]), pkbf(a1[6],a1[7]));
    fA2.u = make_uint4(pkbf(a2[0],a2[1]), pkbf(a2[2],a2[3]), pkbf(a2[4],a2[5]), pkbf(a2[6],a2[7]));
    U4 b0, b1, b2, b3, b4, b5;
    b0.u = B.b[0]; b1.u = B.b[1]; b2.u = B.b[2];
    b3.u = B.b[3]; b4.u = B.b[4]; b5.u = B.b[5];
    __builtin_amdgcn_s_setprio(1);
    acc0 = MFMA32(fA0.s, b0.s, acc0, 0, 0, 0);
    acc1 = MFMA32(fA0.s, b1.s, acc1, 0, 0, 0);
    acc0 = MFMA32(fA1.s, b2.s, acc0, 0, 0, 0);
    acc1 = MFMA32(fA1.s, b3.s, acc1, 0, 0, 0);
    acc0 = MFMA32(fA2.s, b4.s, acc0, 0, 0, 0);
    acc1 = MFMA32(fA2.s, b5.s, acc1, 0, 0, 0);
    __builtin_amdgcn_s_setprio(0);
  };

  BSet Ba, Bb;
  unsigned int Ya[5], Yb[5];
  ldB(0, Ba); ldYh(0, Ya);
  ldB(1, Bb); ldYh(1, Yb);

#pragma unroll 1
  for (int s = 0; s < 64; s += 2){
    agen_mfma(Ya, Ba);
    const int s2 = (s + 2 < 64) ? s + 2 : 63;
    ldB(s2, Ba); ldYh(s2, Ya);
    agen_mfma(Yb, Bb);
    const int s3 = (s + 3 < 64) ? s + 3 : 63;
    ldB(s3, Bb); ldYh(s3, Yb);
  }

  // ---- in-WG reduction over gq (serialized through one 8.4KB buffer) ----
  __syncthreads();
#pragma unroll 1
  for (int rr = 1; rr <= 3; ++rr){
    if (gq == rr){
#pragma unroll
      for (int e = 0; e < 16; ++e){
        red[lane][e]      = acc0[e];
        red[lane][16 + e] = acc1[e];
      }
    }
    __syncthreads();
    if (gq == 0){
#pragma unroll
      for (int e = 0; e < 16; ++e){
        acc0[e] += red[lane][e];
        acc1[e] += red[lane][16 + e];
      }
    }
    __syncthreads();
  }
  if (gq == 0){
#pragma unroll
    for (int e = 0; e < 16; ++e){
      int rowm = (e & 3) + 8*(e >> 2) + 4*h;
      float* d = mix + (size_t)(pbase + rowm)*128 + nh*64 + pr;
      d[0]  = acc0[e];
      d[32] = acc1[e];
    }
  }
}

// ---------------- MLP core: mix -> MLP -> final einsum -> ox/oy (bf16, global) ----------------
__global__ __launch_bounds__(256, 1)
void mlp_core(const ushort_t* __restrict__ whfrag,
              const ushort_t* __restrict__ wffrag,
              const float* __restrict__ mix,
              ushort_t* __restrict__ oxg, ushort_t* __restrict__ oyg){
  extern __shared__ char ldsm[];
  ushort_t* hw = (ushort_t*)ldsm;
  const int t = threadIdx.x;
  const long pbase = (long)blockIdx.x * 32;

  {  // load mix -> act buf0 (bf16)
    int p = t >> 3, n0 = (t & 7) * 16;
    const float* src = mix + (pbase + p)*128 + n0;
    int path = n0 >> 6, nn = n0 & 63;
    ushort_t* dst = hw + (path*2)*2176 + p*68 + nn;
#pragma unroll
    for (int q2 = 0; q2 < 16; ++q2) dst[q2] = f2bf(src[q2]);
  }
  __syncthreads();

  const int w = t >> 6, lane = t & 63;
  const int path = w >> 1, ntw = w & 1;
  const int prow = lane & 31, h = lane >> 5;
  int cur = 0;

#pragma unroll
  for (int layer = 0; layer < 2; ++layer){
    const ushort_t* act = hw + (path*2 + cur)*2176;
    f32x16 acc;
#pragma unroll
    for (int r = 0; r < 16; ++r) acc[r] = 0.f;
#pragma unroll
    for (int c = 0; c < 4; ++c){
      int ab = prow*68 + c*16 + 4*h;
      ushort4 lo = *(const ushort4*)&act[ab];
      ushort4 hi = *(const ushort4*)&act[ab + 8];
      short8 av; av[0]=lo.x; av[1]=lo.y; av[2]=lo.z; av[3]=lo.w;
      av[4]=hi.x; av[5]=hi.y; av[6]=hi.z; av[7]=hi.w;
      short8 bv = *(const short8*)(whfrag + ((((layer*2 + path)*4 + c)*2 + ntw)*512 + lane*8));
      acc = MFMA32(av, bv, acc, 0, 0, 0);
    }
    ushort_t* nact = hw + (path*2 + (cur ^ 1))*2176;
#pragma unroll
    for (int r = 0; r < 16; ++r){
      int p = (r & 3) + 8*(r >> 2) + 4*h;
      nact[p*68 + ntw*32 + prow] = f2bf(tanh_fast(acc[r]));
    }
    cur ^= 1;
    __syncthreads();
  }

  {  // final einsum: o[p][n=l*64+f], N=192 -> each wave 3 n-tiles; write global
    const ushort_t* act = hw + (path*2 + cur)*2176;
    ushort_t* og = (path ? oyg : oxg) + (size_t)pbase * 196;
#pragma unroll
    for (int e = 0; e < 3; ++e){
      int ntf = ntw*3 + e;
      f32x16 acc;
#pragma unroll
      for (int r = 0; r < 16; ++r) acc[r] = 0.f;
#pragma unroll
      for (int c = 0; c < 4; ++c){
        int ab = prow*68 + c*16 + 4*h;
        ushort4 lo = *(const ushort4*)&act[ab];
        ushort4 hi = *(const ushort4*)&act[ab + 8];
        short8 av; av[0]=lo.x; av[1]=lo.y; av[2]=lo.z; av[3]=lo.w;
        av[4]=hi.x; av[5]=hi.y; av[6]=hi.z; av[7]=hi.w;
        short8 bv = *(const short8*)(wffrag + (((path*4 + c)*6 + ntf)*512 + lane*8));
        acc = MFMA32(av, bv, acc, 0, 0, 0);
      }
#pragma unroll
      for (int r = 0; r < 16; ++r){
        int p = (r & 3) + 8*(r >> 2) + 4*h;
        og[(size_t)p*196 + ntf*32 + prow] = f2bf(tanh_fast(acc[r]));
      }
    }
  }
}

// ---------------- epilogue: out = ox[deg]*x*gate + oy[deg]*y (coalesced) ----------------
__global__ __launch_bounds__(256)
void epilogue_k(const float* __restrict__ x, const float* __restrict__ y,
                const ushort_t* __restrict__ oxg, const ushort_t* __restrict__ oyg,
                float* __restrict__ out){
  __shared__ float xs[2304], ys[2304], os[2304];
  const int t = threadIdx.x;
  const long pbase = (long)blockIdx.x * 4;
  const float4* xb = (const float4*)(x + pbase*576);
  const float4* yb = (const float4*)(y + pbase*576);
#pragma unroll
  for (int c = 0; c < 3; ++c){
    int q = t + c*256;
    if (q < 576){
      ((float4*)xs)[q] = xb[q];
      ((float4*)ys)[q] = yb[q];
    }
  }
  __syncthreads();

  const int pp = t >> 6, fq = t & 63;
  {
    const float* xr = &xs[pp*576 + fq*9];
    const float* yr = &ys[pp*576 + fq*9];
    float xv[9], yv[9];
#pragma unroll
    for (int s = 0; s < 9; ++s){ xv[s] = xr[s]; yv[s] = yr[s]; }
    float c0 = xv[2]*yv[3] - xv[3]*yv[2];
    float c1 = xv[3]*yv[1] - xv[1]*yv[3];
    float c2 = xv[1]*yv[2] - xv[2]*yv[1];
    float gate = c0*yv[0] + c1*yv[1] + c2*yv[2];
    const size_t prow = (size_t)(pbase + pp) * 196;
    float ox0 = bf2f(oxg[prow + fq]);
    float ox1 = bf2f(oxg[prow + 64 + fq]);
    float ox2 = bf2f(oxg[prow + 128 + fq]);
    float oy0 = bf2f(oyg[prow + fq]);
    float oy1 = bf2f(oyg[prow + 64 + fq]);
    float oy2 = bf2f(oyg[prow + 128 + fq]);
    float* orow = &os[pp*576 + fq*9];
    orow[0] = ox0*xv[0]*gate + oy0*yv[0];
#pragma unroll
    for (int s = 1; s < 4; ++s) orow[s] = ox1*xv[s]*gate + oy1*yv[s];
#pragma unroll
    for (int s = 4; s < 9; ++s) orow[s] = ox2*xv[s]*gate + oy2*yv[s];
  }
  __syncthreads();

  float4* ob = (float4*)(out + pbase*576);
#pragma unroll
  for (int c = 0; c < 3; ++c){
    int q = t + c*256;
    if (q < 576) ob[q] = ((const float4*)os)[q];
  }
}

extern "C" void kernel_launch(void* const* d_in, const int* in_sizes, int n_in,
                              void* d_out, int out_size, void* d_ws, size_t ws_size,
                              hipStream_t stream){
  (void)in_sizes; (void)n_in; (void)out_size; (void)ws_size;
  const float* x   = (const float*)d_in[0];
  const float* y   = (const float*)d_in[1];
  const float* wx0 = (const float*)d_in[2];
  const float* wy0 = (const float*)d_in[3];
  const float* wxh = (const float*)d_in[4];
  const float* wyh = (const float*)d_in[5];
  const float* wxf = (const float*)d_in[6];
  const float* wyf = (const float*)d_in[7];
  float* out = (float*)d_out;
  char* ws = (char*)d_ws;
  ushort_t* wfrag  = (ushort_t*)(ws);              //  3,145,728 B
  ushort_t* whfrag = (ushort_t*)(ws + 3145728);    //     32,768 B
  ushort_t* wffrag = (ushort_t*)(ws + 3178496);    //     49,152 B
  float* mix       = (float*)(ws + 3227648);       //  4,194,304 B
  ushort_t* oxg    = (ushort_t*)(ws + 7421952);    //  3,211,264 B
  ushort_t* oyg    = (ushort_t*)(ws + 10633216);   //  3,211,264 B

  (void)hipFuncSetAttribute((const void*)gemm10,
        hipFuncAttributeMaxDynamicSharedMemorySize, 50048);

  hipLaunchKernelGGL(bake_w0, dim3(2048), dim3(256), 0, stream, wx0, wy0, wfrag);
  hipLaunchKernelGGL(bake_ws, dim3(20),   dim3(256), 0, stream, wxh, wyh, wxf, wyf, whfrag, wffrag);
  hipLaunchKernelGGL(gemm10,  dim3(512),  dim3(256), 50048, stream, x, y, wfrag, mix);
  hipLaunchKernelGGL(mlp_core, dim3(256), dim3(256), 17408, stream, whfrag, wffrag, mix, oxg, oyg);
  hipLaunchKernelGGL(epilogue_k, dim3(2048), dim3(256), 0, stream, x, y, oxg, oyg, out);
}

// Round 19
// 82.799 us; speedup vs baseline: 1.1899x; 1.0003x over previous
//
#include <hip/hip_runtime.h>
#include <hip/hip_bf16.h>

typedef __attribute__((ext_vector_type(8))) short short8;
typedef __attribute__((ext_vector_type(16))) float f32x16;
typedef __fp16 h2 __attribute__((ext_vector_type(2)));
typedef unsigned short ushort_t;

#define DEVFN static __device__ __forceinline__
#define MFMA32 __builtin_amdgcn_mfma_f32_32x32x16_bf16

DEVFN float bf2f(unsigned short u){
  union { unsigned int i; float f; } v; v.i = ((unsigned int)u) << 16; return v.f;
}
DEVFN unsigned short f2bf(float f){
  unsigned int u = __float_as_uint(f);
  unsigned int r = u + 0x7FFFu + ((u >> 16) & 1u);
  return (unsigned short)(r >> 16);
}
DEVFN unsigned int pkbf(float a, float b){
  unsigned int r;
  asm("v_cvt_pk_bf16_f32 %0, %1, %2" : "=v"(r) : "v"(a), "v"(b));
  return r;
}
DEVFN h2 pkrtz(float a, float b){ return __builtin_amdgcn_cvt_pkrtz(a, b); }
DEVFN h2 u2h(unsigned int u){ union { unsigned int u; h2 h; } v; v.u = u; return v.h; }
// HW 2-way f16 dot with f32 accumulate (verified round 15)
DEVFN float dot2(h2 a, h2 b, float c){
  float r;
  asm("v_dot2_f32_f16 %0, %1, %2, %3" : "=v"(r) : "v"(a), "v"(b), "v"(c));
  return r;
}
DEVFN float tanh_fast(float x){
  float t = __builtin_amdgcn_exp2f(x * 2.885390081777926815f);
  return 1.0f - 2.0f * __builtin_amdgcn_rcpf(t + 1.0f);
}
// shared A/B K-slot mapping for 32x32x16 MFMA fragments
DEVFN int kmap(int h, int j){ return 4*h + (j & 3) + 8*(j >> 2); }

// ---------------- weight bake (coalesced reads, scattered stores) ----------------
// wfrag (hw): ((f*4 + gq)*2 + nh)*3072 + (l*2 + nt)*512 + lane*8 + j
__global__ void bake_w0(const float* __restrict__ wx0, const float* __restrict__ wy0,
                        ushort_t* __restrict__ wfrag){
  int idx = blockIdx.x * 256 + threadIdx.x;   // < 524288
  int g = idx & 63; int r = idx >> 6;
  int f = r & 63; r >>= 6;
  int k = r & 63; int path = r >> 6;
  const float* w = path ? wy0 : wx0;
  const float* src = w + ((size_t)(k*64 + f)*64 + g)*3;
  float v0 = src[0], v1 = src[1], v2 = src[2];      // coalesced (12B stride over g)
  int gq = g >> 4, gl = g & 15;
  int h = (gl >> 2) & 1;
  int j = (gl & 3) | ((gl >> 3) << 2);
  int lane = h*32 + (k & 31);
  int nt = k >> 5;
  size_t base = (size_t)((f*4 + gq)*2 + path)*3072 + (size_t)lane*8 + j;
  wfrag[base + 0*512 + (size_t)nt*512] = f2bf(v0);           // l=0
  wfrag[base + 2*512 + (size_t)nt*512] = f2bf(v1);           // l=1
  wfrag[base + 4*512 + (size_t)nt*512] = f2bf(v2);           // l=2
}

// merged small-weight bake: blocks 0..7 -> whfrag (2048 slots), 8..19 -> wffrag (3072 slots)
__global__ void bake_ws(const float* __restrict__ wxh, const float* __restrict__ wyh,
                        const float* __restrict__ wxf, const float* __restrict__ wyf,
                        ushort_t* __restrict__ whfrag, ushort_t* __restrict__ wffrag){
  int bid = blockIdx.x;
  if (bid < 8){
    int slot = bid * 256 + threadIdx.x;           // < 2048
    int lane = slot & 63;
    int q = slot >> 6;
    int nt = q & 1; q >>= 1;
    int c  = q & 3; q >>= 2;
    int path = q & 1; int layer = q >> 1;
    const float* w = path ? wyh : wxh;
    int n = nt*32 + (lane & 31);
    int h = lane >> 5;
    unsigned int pk[4];
#pragma unroll
    for (int jj = 0; jj < 4; ++jj){
      int k0 = c*16 + kmap(h, 2*jj);
      int k1 = c*16 + kmap(h, 2*jj + 1);
      unsigned int b0 = f2bf(w[layer*4096 + k0*64 + n]);
      unsigned int b1 = f2bf(w[layer*4096 + k1*64 + n]);
      pk[jj] = b0 | (b1 << 16);
    }
    *reinterpret_cast<uint4*>(whfrag + (size_t)slot * 8) = make_uint4(pk[0], pk[1], pk[2], pk[3]);
  } else {
    int slot = (bid - 8) * 256 + threadIdx.x;     // < 3072
    int lane = slot & 63;
    int q = slot >> 6;            // < 48
    int ntf = q % 6;
    int q2 = q / 6;
    int c = q2 & 3; int path = q2 >> 2;
    const float* w = path ? wyf : wxf;
    int n = ntf*32 + (lane & 31);
    int lw = n >> 6, fw = n & 63;
    int h = lane >> 5;
    unsigned int pk[4];
#pragma unroll
    for (int jj = 0; jj < 4; ++jj){
      int k0 = c*16 + kmap(h, 2*jj);
      int k1 = c*16 + kmap(h, 2*jj + 1);
      unsigned int b0 = f2bf(w[(lw*64 + fw)*64 + k0]);
      unsigned int b1 = f2bf(w[(lw*64 + fw)*64 + k1]);
      pk[jj] = b0 | (b1 << 16);
    }
    *reinterpret_cast<uint4*>(wffrag + (size_t)slot * 8) = make_uint4(pk[0], pk[1], pk[2], pk[3]);
  }
}

// ---------------- main fused GEMM (round-15 structure + s_setprio) ----------------
// Grid 512 = Mblk(256, 32 pts) x nh(2); WG 256 thr = 4 waves = gq quarters.
// LDS: YH f16 [32 p][325 dwords] @0 (41600 B) ; red [64][33] f32 @41600 (8448 B)
struct BSet { uint4 b[6]; };
union U4 { uint4 u; short8 s; };

__global__ __launch_bounds__(256)
void gemm10(const float* __restrict__ x, const float* __restrict__ y,
            const ushort_t* __restrict__ wfrag, float* __restrict__ mix){
  extern __shared__ char lds[];
  unsigned int* YHd = (unsigned int*)lds;                 // [32][325] dwords
  ushort_t* YHh = (ushort_t*)lds;
  float (*red)[33] = (float (*)[33])(lds + 41600);        // [64][33]

  const int bid = blockIdx.x;
  const int id = (bid & 7)*64 + (bid >> 3);               // XCD-chunked bijection
  const int nh = id & 1, mb = id >> 1;
  const int pbase = mb * 32;

  const int t = threadIdx.x, lane = t & 63, gq = t >> 6;
  const int h = lane >> 5, pr = lane & 31;

  const float* yb = y + (size_t)pbase * 576;

  // ---- stage y as f16 into LDS (coalesced float4 reads) ----
#pragma unroll
  for (int c = 0; c < 18; ++c){
    int q = t + c*256;                 // < 4608
    int p = q / 144, off = (q - p*144) * 4;
    float4 v = *(const float4*)(yb + p*576 + off);
#pragma unroll
    for (int i = 0; i < 4; ++i){
      int flat = off + i;
      int f = flat / 9, s = flat - f*9;
      float vv = (i==0) ? v.x : (i==1) ? v.y : (i==2) ? v.z : v.w;
      union { __fp16 hf; ushort_t u; } cv; cv.hf = (__fp16)vv;
      YHh[p*650 + f*10 + s] = cv.u;
    }
  }
  __syncthreads();

  // ---- xg init: x via per-lane scalar loads (one-time), y from LDS ----
  h2 xg[8][5];
#pragma unroll
  for (int j = 0; j < 8; ++j){
    const int g = gq*16 + kmap(h, j);
    const float* xp = x + (size_t)(pbase + pr)*576 + g*9;
    unsigned int yd0 = YHd[pr*325 + g*5 + 0];
    unsigned int yd1 = YHd[pr*325 + g*5 + 1];
    h2 y01 = u2h(yd0), y23v = u2h(yd1);
    float y0 = (float)y01[0], y1 = (float)y01[1];
    float y2 = (float)y23v[0], y3 = (float)y23v[1];
    float x1 = xp[1], x2 = xp[2], x3 = xp[3];
    float gate = (x2*y3 - x3*y2)*y0 + (x3*y1 - x1*y3)*y1 + (x1*y2 - x2*y1)*y2;
    xg[j][0] = pkrtz(xp[0]*gate, x1*gate);
    xg[j][1] = pkrtz(x2*gate, x3*gate);
    xg[j][2] = pkrtz(xp[4]*gate, xp[5]*gate);
    xg[j][3] = pkrtz(xp[6]*gate, xp[7]*gate);
    xg[j][4] = pkrtz(xp[8]*gate, 0.f);
  }

  // ---- main loop ----
  f32x16 acc0, acc1;
#pragma unroll
  for (int e = 0; e < 16; ++e){ acc0[e] = 0.f; acc1[e] = 0.f; }

  const ushort_t* wt = wfrag + (size_t)(gq*2 + nh)*3072 + (size_t)lane*8;
  const unsigned int* yrow = YHd + pr*325;

  auto ldB = [&](int f, BSet& B){
    const ushort_t* p0 = wt + (size_t)f * 24576;
#pragma unroll
    for (int i = 0; i < 6; ++i) B.b[i] = *reinterpret_cast<const uint4*>(p0 + i*512);
  };
  auto ldYh = [&](int f, unsigned int* Yr){
#pragma unroll
    for (int d = 0; d < 5; ++d) Yr[d] = yrow[f*5 + d];
  };
  auto agen_mfma = [&](const unsigned int* Yr, const BSet& B){
    h2 y0m = u2h(Yr[0] & 0xFFFFu);
    h2 y1m = u2h(Yr[0] & 0xFFFF0000u);
    h2 y23 = u2h(Yr[1]), y45 = u2h(Yr[2]), y67 = u2h(Yr[3]);
    h2 y8p = u2h(Yr[4] & 0xFFFFu);
    float a0[8], a1[8], a2[8];
#pragma unroll
    for (int j = 0; j < 8; ++j){
      a0[j] = dot2(xg[j][0], y0m, 0.f);
      a1[j] = dot2(xg[j][1], y23, dot2(xg[j][0], y1m, 0.f));
      a2[j] = dot2(xg[j][4], y8p, dot2(xg[j][3], y67, dot2(xg[j][2], y45, 0.f)));
    }
    U4 fA0, fA1, fA2;
    fA0.u = make_uint4(pkbf(a0[0],a0[1]), pkbf(a0[2],a0[3]), pkbf(a0[4],a0[5]), pkbf(a0[6],a0[7]));
    fA1.u = make_uint4(pkbf(a1[0],a1[1]), pkbf(a1[2],a1[3]), pkbf(a1[4],a1[5]), pkbf(a1[6],a1[7]));
    fA2.u = make_uint4(pkbf(a2[0],a2[1]), pkbf(a2[2],a2[3]), pkbf(a2[4],a2[5]), pkbf(a2[6],a2[7]));
    U4 b0, b1, b2, b3, b4, b5;
    b0.u = B.b[0]; b1.u = B.b[1]; b2.u = B.b[2];
    b3.u = B.b[3]; b4.u = B.b[4]; b5.u = B.b[5];
    __builtin_amdgcn_s_setprio(1);
    acc0 = MFMA32(fA0.s, b0.s, acc0, 0, 0, 0);
    acc1 = MFMA32(fA0.s, b1.s, acc1, 0, 0, 0);
    acc0 = MFMA32(fA1.s, b2.s, acc0, 0, 0, 0);
    acc1 = MFMA32(fA1.s, b3.s, acc1, 0, 0, 0);
    acc0 = MFMA32(fA2.s, b4.s, acc0, 0, 0, 0);
    acc1 = MFMA32(fA2.s, b5.s, acc1, 0, 0, 0);
    __builtin_amdgcn_s_setprio(0);
  };

  BSet Ba, Bb;
  unsigned int Ya[5], Yb[5];
  ldB(0, Ba); ldYh(0, Ya);
  ldB(1, Bb); ldYh(1, Yb);

#pragma unroll 1
  for (int s = 0; s < 64; s += 2){
    agen_mfma(Ya, Ba);
    const int s2 = (s + 2 < 64) ? s + 2 : 63;
    ldB(s2, Ba); ldYh(s2, Ya);
    agen_mfma(Yb, Bb);
    const int s3 = (s + 3 < 64) ? s + 3 : 63;
    ldB(s3, Bb); ldYh(s3, Yb);
  }

  // ---- in-WG reduction over gq (serialized through one 8.4KB buffer) ----
  __syncthreads();
#pragma unroll 1
  for (int rr = 1; rr <= 3; ++rr){
    if (gq == rr){
#pragma unroll
      for (int e = 0; e < 16; ++e){
        red[lane][e]      = acc0[e];
        red[lane][16 + e] = acc1[e];
      }
    }
    __syncthreads();
    if (gq == 0){
#pragma unroll
      for (int e = 0; e < 16; ++e){
        acc0[e] += red[lane][e];
        acc1[e] += red[lane][16 + e];
      }
    }
    __syncthreads();
  }
  if (gq == 0){
#pragma unroll
    for (int e = 0; e < 16; ++e){
      int rowm = (e & 3) + 8*(e >> 2) + 4*h;
      float* d = mix + (size_t)(pbase + rowm)*128 + nh*64 + pr;
      d[0]  = acc0[e];
      d[32] = acc1[e];
    }
  }
}

// ---------------- MLP core: mix -> MLP -> final einsum -> ox/oy (bf16, global) ----------------
__global__ __launch_bounds__(256, 1)
void mlp_core(const ushort_t* __restrict__ whfrag,
              const ushort_t* __restrict__ wffrag,
              const float* __restrict__ mix,
              ushort_t* __restrict__ oxg, ushort_t* __restrict__ oyg){
  extern __shared__ char ldsm[];
  ushort_t* hw = (ushort_t*)ldsm;
  const int t = threadIdx.x;
  const long pbase = (long)blockIdx.x * 32;

  {  // load mix -> act buf0 (bf16)
    int p = t >> 3, n0 = (t & 7) * 16;
    const float* src = mix + (pbase + p)*128 + n0;
    int path = n0 >> 6, nn = n0 & 63;
    ushort_t* dst = hw + (path*2)*2176 + p*68 + nn;
#pragma unroll
    for (int q2 = 0; q2 < 16; ++q2) dst[q2] = f2bf(src[q2]);
  }
  __syncthreads();

  const int w = t >> 6, lane = t & 63;
  const int path = w >> 1, ntw = w & 1;
  const int prow = lane & 31, h = lane >> 5;
  int cur = 0;

#pragma unroll
  for (int layer = 0; layer < 2; ++layer){
    const ushort_t* act = hw + (path*2 + cur)*2176;
    f32x16 acc;
#pragma unroll
    for (int r = 0; r < 16; ++r) acc[r] = 0.f;
#pragma unroll
    for (int c = 0; c < 4; ++c){
      int ab = prow*68 + c*16 + 4*h;
      ushort4 lo = *(const ushort4*)&act[ab];
      ushort4 hi = *(const ushort4*)&act[ab + 8];
      short8 av; av[0]=lo.x; av[1]=lo.y; av[2]=lo.z; av[3]=lo.w;
      av[4]=hi.x; av[5]=hi.y; av[6]=hi.z; av[7]=hi.w;
      short8 bv = *(const short8*)(whfrag + ((((layer*2 + path)*4 + c)*2 + ntw)*512 + lane*8));
      acc = MFMA32(av, bv, acc, 0, 0, 0);
    }
    ushort_t* nact = hw + (path*2 + (cur ^ 1))*2176;
#pragma unroll
    for (int r = 0; r < 16; ++r){
      int p = (r & 3) + 8*(r >> 2) + 4*h;
      nact[p*68 + ntw*32 + prow] = f2bf(tanh_fast(acc[r]));
    }
    cur ^= 1;
    __syncthreads();
  }

  {  // final einsum: o[p][n=l*64+f], N=192 -> each wave 3 n-tiles; write global
    const ushort_t* act = hw + (path*2 + cur)*2176;
    ushort_t* og = (path ? oyg : oxg) + (size_t)pbase * 196;
#pragma unroll
    for (int e = 0; e < 3; ++e){
      int ntf = ntw*3 + e;
      f32x16 acc;
#pragma unroll
      for (int r = 0; r < 16; ++r) acc[r] = 0.f;
#pragma unroll
      for (int c = 0; c < 4; ++c){
        int ab = prow*68 + c*16 + 4*h;
        ushort4 lo = *(const ushort4*)&act[ab];
        ushort4 hi = *(const ushort4*)&act[ab + 8];
        short8 av; av[0]=lo.x; av[1]=lo.y; av[2]=lo.z; av[3]=lo.w;
        av[4]=hi.x; av[5]=hi.y; av[6]=hi.z; av[7]=hi.w;
        short8 bv = *(const short8*)(wffrag + (((path*4 + c)*6 + ntf)*512 + lane*8));
        acc = MFMA32(av, bv, acc, 0, 0, 0);
      }
#pragma unroll
      for (int r = 0; r < 16; ++r){
        int p = (r & 3) + 8*(r >> 2) + 4*h;
        og[(size_t)p*196 + ntf*32 + prow] = f2bf(tanh_fast(acc[r]));
      }
    }
  }
}

// ---------------- epilogue: out = ox[deg]*x*gate + oy[deg]*y (coalesced) ----------------
__global__ __launch_bounds__(256)
void epilogue_k(const float* __restrict__ x, const float* __restrict__ y,
                const ushort_t* __restrict__ oxg, const ushort_t* __restrict__ oyg,
                float* __restrict__ out){
  __shared__ float xs[2304], ys[2304], os[2304];
  const int t = threadIdx.x;
  const long pbase = (long)blockIdx.x * 4;
  const float4* xb = (const float4*)(x + pbase*576);
  const float4* yb = (const float4*)(y + pbase*576);
#pragma unroll
  for (int c = 0; c < 3; ++c){
    int q = t + c*256;
    if (q < 576){
      ((float4*)xs)[q] = xb[q];
      ((float4*)ys)[q] = yb[q];
    }
  }
  __syncthreads();

  const int pp = t >> 6, fq = t & 63;
  {
    const float* xr = &xs[pp*576 + fq*9];
    const float* yr = &ys[pp*576 + fq*9];
    float xv[9], yv[9];
#pragma unroll
    for (int s = 0; s < 9; ++s){ xv[s] = xr[s]; yv[s] = yr[s]; }
    float c0 = xv[2]*yv[3] - xv[3]*yv[2];
    float c1 = xv[3]*yv[1] - xv[1]*yv[3];
    float c2 = xv[1]*yv[2] - xv[2]*yv[1];
    float gate = c0*yv[0] + c1*yv[1] + c2*yv[2];
    const size_t prow = (size_t)(pbase + pp) * 196;
    float ox0 = bf2f(oxg[prow + fq]);
    float ox1 = bf2f(oxg[prow + 64 + fq]);
    float ox2 = bf2f(oxg[prow + 128 + fq]);
    float oy0 = bf2f(oyg[prow + fq]);
    float oy1 = bf2f(oyg[prow + 64 + fq]);
    float oy2 = bf2f(oyg[prow + 128 + fq]);
    float* orow = &os[pp*576 + fq*9];
    orow[0] = ox0*xv[0]*gate + oy0*yv[0];
#pragma unroll
    for (int s = 1; s < 4; ++s) orow[s] = ox1*xv[s]*gate + oy1*yv[s];
#pragma unroll
    for (int s = 4; s < 9; ++s) orow[s] = ox2*xv[s]*gate + oy2*yv[s];
  }
  __syncthreads();

  float4* ob = (float4*)(out + pbase*576);
#pragma unroll
  for (int c = 0; c < 3; ++c){
    int q = t + c*256;
    if (q < 576) ob[q] = ((const float4*)os)[q];
  }
}

extern "C" void kernel_launch(void* const* d_in, const int* in_sizes, int n_in,
                              void* d_out, int out_size, void* d_ws, size_t ws_size,
                              hipStream_t stream){
  (void)in_sizes; (void)n_in; (void)out_size; (void)ws_size;
  const float* x   = (const float*)d_in[0];
  const float* y   = (const float*)d_in[1];
  const float* wx0 = (const float*)d_in[2];
  const float* wy0 = (const float*)d_in[3];
  const float* wxh = (const float*)d_in[4];
  const float* wyh = (const float*)d_in[5];
  const float* wxf = (const float*)d_in[6];
  const float* wyf = (const float*)d_in[7];
  float* out = (float*)d_out;
  char* ws = (char*)d_ws;
  ushort_t* wfrag  = (ushort_t*)(ws);              //  3,145,728 B
  ushort_t* whfrag = (ushort_t*)(ws + 3145728);    //     32,768 B
  ushort_t* wffrag = (ushort_t*)(ws + 3178496);    //     49,152 B
  float* mix       = (float*)(ws + 3227648);       //  4,194,304 B
  ushort_t* oxg    = (ushort_t*)(ws + 7421952);    //  3,211,264 B
  ushort_t* oyg    = (ushort_t*)(ws + 10633216);   //  3,211,264 B

  (void)hipFuncSetAttribute((const void*)gemm10,
        hipFuncAttributeMaxDynamicSharedMemorySize, 50048);

  hipLaunchKernelGGL(bake_w0, dim3(2048), dim3(256), 0, stream, wx0, wy0, wfrag);
  hipLaunchKernelGGL(bake_ws, dim3(20),   dim3(256), 0, stream, wxh, wyh, wxf, wyf, whfrag, wffrag);
  hipLaunchKernelGGL(gemm10,  dim3(512),  dim3(256), 50048, stream, x, y, wfrag, mix);
  hipLaunchKernelGGL(mlp_core, dim3(256), dim3(256), 17408, stream, whfrag, wffrag, mix, oxg, oyg);
  hipLaunchKernelGGL(epilogue_k, dim3(2048), dim3(256), 0, stream, x, y, oxg, oyg, out);
}

// Round 21
// 82.647 us; speedup vs baseline: 1.1921x; 1.0018x over previous
//
#include <hip/hip_runtime.h>
#include <hip/hip_bf16.h>

typedef __attribute__((ext_vector_type(8))) short short8;
typedef __attribute__((ext_vector_type(16))) float f32x16;
typedef __fp16 h2 __attribute__((ext_vector_type(2)));
typedef unsigned short ushort_t;

#define DEVFN static __device__ __forceinline__
#define MFMA32 __builtin_amdgcn_mfma_f32_32x32x16_bf16

DEVFN float bf2f(unsigned short u){
  union { unsigned int i; float f; } v; v.i = ((unsigned int)u) << 16; return v.f;
}
DEVFN unsigned short f2bf(float f){
  unsigned int u = __float_as_uint(f);
  unsigned int r = u + 0x7FFFu + ((u >> 16) & 1u);
  return (unsigned short)(r >> 16);
}
DEVFN unsigned int pkbf(float a, float b){
  unsigned int r;
  asm("v_cvt_pk_bf16_f32 %0, %1, %2" : "=v"(r) : "v"(a), "v"(b));
  return r;
}
DEVFN h2 pkrtz(float a, float b){ return __builtin_amdgcn_cvt_pkrtz(a, b); }
DEVFN h2 u2h(unsigned int u){ union { unsigned int u; h2 h; } v; v.u = u; return v.h; }
// HW 2-way f16 dot with f32 accumulate (verified round 15)
DEVFN float dot2(h2 a, h2 b, float c){
  float r;
  asm("v_dot2_f32_f16 %0, %1, %2, %3" : "=v"(r) : "v"(a), "v"(b), "v"(c));
  return r;
}
DEVFN float tanh_fast(float x){
  float t = __builtin_amdgcn_exp2f(x * 2.885390081777926815f);
  return 1.0f - 2.0f * __builtin_amdgcn_rcpf(t + 1.0f);
}
// shared A/B K-slot mapping for 32x32x16 MFMA fragments
DEVFN int kmap(int h, int j){ return 4*h + (j & 3) + 8*(j >> 2); }

// ---------------- weight bake (coalesced reads, scattered stores) ----------------
// wfrag (hw): ((f*4 + gq)*2 + nh)*3072 + (l*2 + nt)*512 + lane*8 + j
__global__ void bake_w0(const float* __restrict__ wx0, const float* __restrict__ wy0,
                        ushort_t* __restrict__ wfrag){
  int idx = blockIdx.x * 256 + threadIdx.x;   // < 524288
  int g = idx & 63; int r = idx >> 6;
  int f = r & 63; r >>= 6;
  int k = r & 63; int path = r >> 6;
  const float* w = path ? wy0 : wx0;
  const float* src = w + ((size_t)(k*64 + f)*64 + g)*3;
  float v0 = src[0], v1 = src[1], v2 = src[2];      // coalesced (12B stride over g)
  int gq = g >> 4, gl = g & 15;
  int h = (gl >> 2) & 1;
  int j = (gl & 3) | ((gl >> 3) << 2);
  int lane = h*32 + (k & 31);
  int nt = k >> 5;
  size_t base = (size_t)((f*4 + gq)*2 + path)*3072 + (size_t)lane*8 + j;
  wfrag[base + 0*512 + (size_t)nt*512] = f2bf(v0);           // l=0
  wfrag[base + 2*512 + (size_t)nt*512] = f2bf(v1);           // l=1
  wfrag[base + 4*512 + (size_t)nt*512] = f2bf(v2);           // l=2
}

// merged small-weight bake: blocks 0..7 -> whfrag (2048 slots), 8..19 -> wffrag (3072 slots)
__global__ void bake_ws(const float* __restrict__ wxh, const float* __restrict__ wyh,
                        const float* __restrict__ wxf, const float* __restrict__ wyf,
                        ushort_t* __restrict__ whfrag, ushort_t* __restrict__ wffrag){
  int bid = blockIdx.x;
  if (bid < 8){
    int slot = bid * 256 + threadIdx.x;           // < 2048
    int lane = slot & 63;
    int q = slot >> 6;
    int nt = q & 1; q >>= 1;
    int c  = q & 3; q >>= 2;
    int path = q & 1; int layer = q >> 1;
    const float* w = path ? wyh : wxh;
    int n = nt*32 + (lane & 31);
    int h = lane >> 5;
    unsigned int pk[4];
#pragma unroll
    for (int jj = 0; jj < 4; ++jj){
      int k0 = c*16 + kmap(h, 2*jj);
      int k1 = c*16 + kmap(h, 2*jj + 1);
      unsigned int b0 = f2bf(w[layer*4096 + k0*64 + n]);
      unsigned int b1 = f2bf(w[layer*4096 + k1*64 + n]);
      pk[jj] = b0 | (b1 << 16);
    }
    *reinterpret_cast<uint4*>(whfrag + (size_t)slot * 8) = make_uint4(pk[0], pk[1], pk[2], pk[3]);
  } else {
    int slot = (bid - 8) * 256 + threadIdx.x;     // < 3072
    int lane = slot & 63;
    int q = slot >> 6;            // < 48
    int ntf = q % 6;
    int q2 = q / 6;
    int c = q2 & 3; int path = q2 >> 2;
    const float* w = path ? wyf : wxf;
    int n = ntf*32 + (lane & 31);
    int lw = n >> 6, fw = n & 63;
    int h = lane >> 5;
    unsigned int pk[4];
#pragma unroll
    for (int jj = 0; jj < 4; ++jj){
      int k0 = c*16 + kmap(h, 2*jj);
      int k1 = c*16 + kmap(h, 2*jj + 1);
      unsigned int b0 = f2bf(w[(lw*64 + fw)*64 + k0]);
      unsigned int b1 = f2bf(w[(lw*64 + fw)*64 + k1]);
      pk[jj] = b0 | (b1 << 16);
    }
    *reinterpret_cast<uint4*>(wffrag + (size_t)slot * 8) = make_uint4(pk[0], pk[1], pk[2], pk[3]);
  }
}

// ---------------- main fused GEMM (round-15 structure + s_setprio) ----------------
// Grid 512 = Mblk(256, 32 pts) x nh(2); WG 256 thr = 4 waves = gq quarters.
// LDS: YH f16 [32 p][325 dwords] @0 (41600 B) ; red [64][33] f32 @41600 (8448 B)
struct BSet { uint4 b[6]; };
union U4 { uint4 u; short8 s; };

__global__ __launch_bounds__(256)
void gemm10(const float* __restrict__ x, const float* __restrict__ y,
            const ushort_t* __restrict__ wfrag, float* __restrict__ mix){
  extern __shared__ char lds[];
  unsigned int* YHd = (unsigned int*)lds;                 // [32][325] dwords
  ushort_t* YHh = (ushort_t*)lds;
  float (*red)[33] = (float (*)[33])(lds + 41600);        // [64][33]

  const int bid = blockIdx.x;
  const int id = (bid & 7)*64 + (bid >> 3);               // XCD-chunked bijection
  const int nh = id & 1, mb = id >> 1;
  const int pbase = mb * 32;

  const int t = threadIdx.x, lane = t & 63, gq = t >> 6;
  const int h = lane >> 5, pr = lane & 31;

  const float* yb = y + (size_t)pbase * 576;

  // ---- stage y as f16 into LDS (coalesced float4 reads) ----
#pragma unroll
  for (int c = 0; c < 18; ++c){
    int q = t + c*256;                 // < 4608
    int p = q / 144, off = (q - p*144) * 4;
    float4 v = *(const float4*)(yb + p*576 + off);
#pragma unroll
    for (int i = 0; i < 4; ++i){
      int flat = off + i;
      int f = flat / 9, s = flat - f*9;
      float vv = (i==0) ? v.x : (i==1) ? v.y : (i==2) ? v.z : v.w;
      union { __fp16 hf; ushort_t u; } cv; cv.hf = (__fp16)vv;
      YHh[p*650 + f*10 + s] = cv.u;
    }
  }
  __syncthreads();

  // ---- xg init: x via per-lane scalar loads (one-time), y from LDS ----
  h2 xg[8][5];
#pragma unroll
  for (int j = 0; j < 8; ++j){
    const int g = gq*16 + kmap(h, j);
    const float* xp = x + (size_t)(pbase + pr)*576 + g*9;
    unsigned int yd0 = YHd[pr*325 + g*5 + 0];
    unsigned int yd1 = YHd[pr*325 + g*5 + 1];
    h2 y01 = u2h(yd0), y23v = u2h(yd1);
    float y0 = (float)y01[0], y1 = (float)y01[1];
    float y2 = (float)y23v[0], y3 = (float)y23v[1];
    float x1 = xp[1], x2 = xp[2], x3 = xp[3];
    float gate = (x2*y3 - x3*y2)*y0 + (x3*y1 - x1*y3)*y1 + (x1*y2 - x2*y1)*y2;
    xg[j][0] = pkrtz(xp[0]*gate, x1*gate);
    xg[j][1] = pkrtz(x2*gate, x3*gate);
    xg[j][2] = pkrtz(xp[4]*gate, xp[5]*gate);
    xg[j][3] = pkrtz(xp[6]*gate, xp[7]*gate);
    xg[j][4] = pkrtz(xp[8]*gate, 0.f);
  }

  // ---- main loop ----
  f32x16 acc0, acc1;
#pragma unroll
  for (int e = 0; e < 16; ++e){ acc0[e] = 0.f; acc1[e] = 0.f; }

  const ushort_t* wt = wfrag + (size_t)(gq*2 + nh)*3072 + (size_t)lane*8;
  const unsigned int* yrow = YHd + pr*325;

  auto ldB = [&](int f, BSet& B){
    const ushort_t* p0 = wt + (size_t)f * 24576;
#pragma unroll
    for (int i = 0; i < 6; ++i) B.b[i] = *reinterpret_cast<const uint4*>(p0 + i*512);
  };
  auto ldYh = [&](int f, unsigned int* Yr){
#pragma unroll
    for (int d = 0; d < 5; ++d) Yr[d] = yrow[f*5 + d];
  };
  auto agen_mfma = [&](const unsigned int* Yr, const BSet& B){
    h2 y0m = u2h(Yr[0] & 0xFFFFu);
    h2 y1m = u2h(Yr[0] & 0xFFFF0000u);
    h2 y23 = u2h(Yr[1]), y45 = u2h(Yr[2]), y67 = u2h(Yr[3]);
    h2 y8p = u2h(Yr[4] & 0xFFFFu);
    float a0[8], a1[8], a2[8];
#pragma unroll
    for (int j = 0; j < 8; ++j){
      a0[j] = dot2(xg[j][0], y0m, 0.f);
      a1[j] = dot2(xg[j][1], y23, dot2(xg[j][0], y1m, 0.f));
      a2[j] = dot2(xg[j][4], y8p, dot2(xg[j][3], y67, dot2(xg[j][2], y45, 0.f)));
    }
    U4 fA0, fA1, fA2;
    fA0.u = make_uint4(pkbf(a0[0],a0[1]), pkbf(a0[2],a0[3]), pkbf(a0[4],a0[5]), pkbf(a0[6],a0[7]));
    fA1.u = make_uint4(pkbf(a1[0],a1[1]), pkbf(a1[2],a1[3]), pkbf(a1[4],a1[5]), pkbf(a1[6],a1[7]));
    fA2.u = make_uint4(pkbf(a2[0],a2[1]), pkbf(a2[2],a2[3]), pkbf(a2[4],a2[5]), pkbf(a2[6],a2[7]));
    U4 b0, b1, b2, b3, b4, b5;
    b0.u = B.b[0]; b1.u = B.b[1]; b2.u = B.b[2];
    b3.u = B.b[3]; b4.u = B.b[4]; b5.u = B.b[5];
    __builtin_amdgcn_s_setprio(1);
    acc0 = MFMA32(fA0.s, b0.s, acc0, 0, 0, 0);
    acc1 = MFMA32(fA0.s, b1.s, acc1, 0, 0, 0);
    acc0 = MFMA32(fA1.s, b2.s, acc0, 0, 0, 0);
    acc1 = MFMA32(fA1.s, b3.s, acc1, 0, 0, 0);
    acc0 = MFMA32(fA2.s, b4.s, acc0, 0, 0, 0);
    acc1 = MFMA32(fA2.s, b5.s, acc1, 0, 0, 0);
    __builtin_amdgcn_s_setprio(0);
  };

  BSet Ba, Bb;
  unsigned int Ya[5], Yb[5];
  ldB(0, Ba); ldYh(0, Ya);
  ldB(1, Bb); ldYh(1, Yb);

#pragma unroll 1
  for (int s = 0; s < 64; s += 2){
    agen_mfma(Ya, Ba);
    const int s2 = (s + 2 < 64) ? s + 2 : 63;
    ldB(s2, Ba); ldYh(s2, Ya);
    agen_mfma(Yb, Bb);
    const int s3 = (s + 3 < 64) ? s + 3 : 63;
    ldB(s3, Bb); ldYh(s3, Yb);
  }

  // ---- in-WG reduction over gq (serialized through one 8.4KB buffer) ----
  __syncthreads();
#pragma unroll 1
  for (int rr = 1; rr <= 3; ++rr){
    if (gq == rr){
#pragma unroll
      for (int e = 0; e < 16; ++e){
        red[lane][e]      = acc0[e];
        red[lane][16 + e] = acc1[e];
      }
    }
    __syncthreads();
    if (gq == 0){
#pragma unroll
      for (int e = 0; e < 16; ++e){
        acc0[e] += red[lane][e];
        acc1[e] += red[lane][16 + e];
      }
    }
    __syncthreads();
  }
  if (gq == 0){
#pragma unroll
    for (int e = 0; e < 16; ++e){
      int rowm = (e & 3) + 8*(e >> 2) + 4*h;
      float* d = mix + (size_t)(pbase + rowm)*128 + nh*64 + pr;
      d[0]  = acc0[e];
      d[32] = acc1[e];
    }
  }
}

// ---------------- MLP core: mix -> MLP -> final einsum -> ox/oy (bf16, global) ----------------
__global__ __launch_bounds__(256, 1)
void mlp_core(const ushort_t* __restrict__ whfrag,
              const ushort_t* __restrict__ wffrag,
              const float* __restrict__ mix,
              ushort_t* __restrict__ oxg, ushort_t* __restrict__ oyg){
  extern __shared__ char ldsm[];
  ushort_t* hw = (ushort_t*)ldsm;
  const int t = threadIdx.x;
  const long pbase = (long)blockIdx.x * 32;

  {  // load mix -> act buf0 (bf16)
    int p = t >> 3, n0 = (t & 7) * 16;
    const float* src = mix + (pbase + p)*128 + n0;
    int path = n0 >> 6, nn = n0 & 63;
    ushort_t* dst = hw + (path*2)*2176 + p*68 + nn;
#pragma unroll
    for (int q2 = 0; q2 < 16; ++q2) dst[q2] = f2bf(src[q2]);
  }
  __syncthreads();

  const int w = t >> 6, lane = t & 63;
  const int path = w >> 1, ntw = w & 1;
  const int prow = lane & 31, h = lane >> 5;
  int cur = 0;

#pragma unroll
  for (int layer = 0; layer < 2; ++layer){
    const ushort_t* act = hw + (path*2 + cur)*2176;
    f32x16 acc;
#pragma unroll
    for (int r = 0; r < 16; ++r) acc[r] = 0.f;
#pragma unroll
    for (int c = 0; c < 4; ++c){
      int ab = prow*68 + c*16 + 4*h;
      ushort4 lo = *(const ushort4*)&act[ab];
      ushort4 hi = *(const ushort4*)&act[ab + 8];
      short8 av; av[0]=lo.x; av[1]=lo.y; av[2]=lo.z; av[3]=lo.w;
      av[4]=hi.x; av[5]=hi.y; av[6]=hi.z; av[7]=hi.w;
      short8 bv = *(const short8*)(whfrag + ((((layer*2 + path)*4 + c)*2 + ntw)*512 + lane*8));
      acc = MFMA32(av, bv, acc, 0, 0, 0);
    }
    ushort_t* nact = hw + (path*2 + (cur ^ 1))*2176;
#pragma unroll
    for (int r = 0; r < 16; ++r){
      int p = (r & 3) + 8*(r >> 2) + 4*h;
      nact[p*68 + ntw*32 + prow] = f2bf(tanh_fast(acc[r]));
    }
    cur ^= 1;
    __syncthreads();
  }

  {  // final einsum: o[p][n=l*64+f], N=192 -> each wave 3 n-tiles; write global
    const ushort_t* act = hw + (path*2 + cur)*2176;
    ushort_t* og = (path ? oyg : oxg) + (size_t)pbase * 196;
#pragma unroll
    for (int e = 0; e < 3; ++e){
      int ntf = ntw*3 + e;
      f32x16 acc;
#pragma unroll
      for (int r = 0; r < 16; ++r) acc[r] = 0.f;
#pragma unroll
      for (int c = 0; c < 4; ++c){
        int ab = prow*68 + c*16 + 4*h;
        ushort4 lo = *(const ushort4*)&act[ab];
        ushort4 hi = *(const ushort4*)&act[ab + 8];
        short8 av; av[0]=lo.x; av[1]=lo.y; av[2]=lo.z; av[3]=lo.w;
        av[4]=hi.x; av[5]=hi.y; av[6]=hi.z; av[7]=hi.w;
        short8 bv = *(const short8*)(wffrag + (((path*4 + c)*6 + ntf)*512 + lane*8));
        acc = MFMA32(av, bv, acc, 0, 0, 0);
      }
#pragma unroll
      for (int r = 0; r < 16; ++r){
        int p = (r & 3) + 8*(r >> 2) + 4*h;
        og[(size_t)p*196 + ntf*32 + prow] = f2bf(tanh_fast(acc[r]));
      }
    }
  }
}

// ---------------- epilogue: out = ox[deg]*x*gate + oy[deg]*y (coalesced) ----------------
__global__ __launch_bounds__(256)
void epilogue_k(const float* __restrict__ x, const float* __restrict__ y,
                const ushort_t* __restrict__ oxg, const ushort_t* __restrict__ oyg,
                float* __restrict__ out){
  __shared__ float xs[2304], ys[2304], os[2304];
  const int t = threadIdx.x;
  const long pbase = (long)blockIdx.x * 4;
  const float4* xb = (const float4*)(x + pbase*576);
  const float4* yb = (const float4*)(y + pbase*576);
#pragma unroll
  for (int c = 0; c < 3; ++c){
    int q = t + c*256;
    if (q < 576){
      ((float4*)xs)[q] = xb[q];
      ((float4*)ys)[q] = yb[q];
    }
  }
  __syncthreads();

  const int pp = t >> 6, fq = t & 63;
  {
    const float* xr = &xs[pp*576 + fq*9];
    const float* yr = &ys[pp*576 + fq*9];
    float xv[9], yv[9];
#pragma unroll
    for (int s = 0; s < 9; ++s){ xv[s] = xr[s]; yv[s] = yr[s]; }
    float c0 = xv[2]*yv[3] - xv[3]*yv[2];
    float c1 = xv[3]*yv[1] - xv[1]*yv[3];
    float c2 = xv[1]*yv[2] - xv[2]*yv[1];
    float gate = c0*yv[0] + c1*yv[1] + c2*yv[2];
    const size_t prow = (size_t)(pbase + pp) * 196;
    float ox0 = bf2f(oxg[prow + fq]);
    float ox1 = bf2f(oxg[prow + 64 + fq]);
    float ox2 = bf2f(oxg[prow + 128 + fq]);
    float oy0 = bf2f(oyg[prow + fq]);
    float oy1 = bf2f(oyg[prow + 64 + fq]);
    float oy2 = bf2f(oyg[prow + 128 + fq]);
    float* orow = &os[pp*576 + fq*9];
    orow[0] = ox0*xv[0]*gate + oy0*yv[0];
#pragma unroll
    for (int s = 1; s < 4; ++s) orow[s] = ox1*xv[s]*gate + oy1*yv[s];
#pragma unroll
    for (int s = 4; s < 9; ++s) orow[s] = ox2*xv[s]*gate + oy2*yv[s];
  }
  __syncthreads();

  float4* ob = (float4*)(out + pbase*576);
#pragma unroll
  for (int c = 0; c < 3; ++c){
    int q = t + c*256;
    if (q < 576) ob[q] = ((const float4*)os)[q];
  }
}

extern "C" void kernel_launch(void* const* d_in, const int* in_sizes, int n_in,
                              void* d_out, int out_size, void* d_ws, size_t ws_size,
                              hipStream_t stream){
  (void)in_sizes; (void)n_in; (void)out_size; (void)ws_size;
  const float* x   = (const float*)d_in[0];
  const float* y   = (const float*)d_in[1];
  const float* wx0 = (const float*)d_in[2];
  const float* wy0 = (const float*)d_in[3];
  const float* wxh = (const float*)d_in[4];
  const float* wyh = (const float*)d_in[5];
  const float* wxf = (const float*)d_in[6];
  const float* wyf = (const float*)d_in[7];
  float* out = (float*)d_out;
  char* ws = (char*)d_ws;
  ushort_t* wfrag  = (ushort_t*)(ws);              //  3,145,728 B
  ushort_t* whfrag = (ushort_t*)(ws + 3145728);    //     32,768 B
  ushort_t* wffrag = (ushort_t*)(ws + 3178496);    //     49,152 B
  float* mix       = (float*)(ws + 3227648);       //  4,194,304 B
  ushort_t* oxg    = (ushort_t*)(ws + 7421952);    //  3,211,264 B
  ushort_t* oyg    = (ushort_t*)(ws + 10633216);   //  3,211,264 B

  (void)hipFuncSetAttribute((const void*)gemm10,
        hipFuncAttributeMaxDynamicSharedMemorySize, 50048);

  hipLaunchKernelGGL(bake_w0, dim3(2048), dim3(256), 0, stream, wx0, wy0, wfrag);
  hipLaunchKernelGGL(bake_ws, dim3(20),   dim3(256), 0, stream, wxh, wyh, wxf, wyf, whfrag, wffrag);
  hipLaunchKernelGGL(gemm10,  dim3(512),  dim3(256), 50048, stream, x, y, wfrag, mix);
  hipLaunchKernelGGL(mlp_core, dim3(256), dim3(256), 17408, stream, whfrag, wffrag, mix, oxg, oyg);
  hipLaunchKernelGGL(epilogue_k, dim3(2048), dim3(256), 0, stream, x, y, oxg, oyg, out);
}